// Round 14
// baseline (585.600 us; speedup 1.0000x reference)
//
#include <hip/hip_runtime.h>

#define E_      262144
#define NNODES  32768
#define L_      2

typedef __attribute__((ext_vector_type(8))) short  bf16x8;
typedef __attribute__((ext_vector_type(4))) float  f32x4;

typedef __attribute__((address_space(1))) const unsigned int gu32;
typedef __attribute__((address_space(3))) unsigned int       lu32;

__device__ __forceinline__ void gl16(const void* g, void* l) {
    // async global->LDS, 16B/lane; LDS dest = wave-uniform base + lane*16
    __builtin_amdgcn_global_load_lds((gu32*)g, (lu32*)l, 16, 0, 0);
}

__device__ __forceinline__ float bf2f(unsigned short u) {
    union { unsigned int i; float f; } v; v.i = ((unsigned int)u) << 16; return v.f;
}
__device__ __forceinline__ unsigned short f2bf(float f) {
    union { float f; unsigned int i; } v; v.f = f;
    unsigned int r = v.i + 0x7FFFu + ((v.i >> 16) & 1u);   // round-nearest-even
    return (unsigned short)(r >> 16);
}

// combined fp32->bf16 for nodes + edge_attr
__global__ __launch_bounds__(256)
void k_cvt2(const float* __restrict__ a, unsigned short* __restrict__ oa, int n4a,
            const float* __restrict__ b, unsigned short* __restrict__ ob, int n4b)
{
    int i = blockIdx.x * 256 + threadIdx.x;
    if (i < n4a) {
        float4 v = reinterpret_cast<const float4*>(a)[i];
        ushort4 o; o.x = f2bf(v.x); o.y = f2bf(v.y); o.z = f2bf(v.z); o.w = f2bf(v.w);
        reinterpret_cast<ushort4*>(oa)[i] = o;
    } else if (i < n4a + n4b) {
        int j = i - n4a;
        float4 v = reinterpret_cast<const float4*>(b)[j];
        ushort4 o; o.x = f2bf(v.x); o.y = f2bf(v.y); o.z = f2bf(v.z); o.w = f2bf(v.w);
        reinterpret_cast<ushort4*>(ob)[j] = o;
    }
}

// batched weight transpose: 13 matrices in one dispatch. [K][N] fp32 -> [N][K] bf16
struct TD  { const float* s; unsigned short* d; int off; int K; int nsh; };
struct TDA { TD v[13]; int total; };

__global__ __launch_bounds__(256)
void k_transpose_all(TDA t)
{
    int idx = blockIdx.x * 256 + threadIdx.x;
    if (idx >= t.total) return;
    int j = 0;
#pragma unroll
    for (int m = 1; m < 13; ++m) if (idx >= t.v[m].off) j = m;
    const TD& td = t.v[j];
    int local = idx - td.off;
    int k = local >> td.nsh;
    int n = local & ((1 << td.nsh) - 1);
    td.d[(size_t)n * td.K + k] = f2bf(td.s[local]);
}

// ---------------------------------------------------------------------------
// FUSED 3-stage edge MLP, BM=64. R12 structure EXCEPT: no A-stage LDS buffer.
// Phase-1 A-fragments are loaded per-lane DIRECTLY from global into VGPRs in
// MFMA fragment layout (wave = 16 random rows x 64B, same requests as the old
// staging; B keeps LDS reuse). The a-loads issue alongside the B gl16s and
// complete at the same barrier drain. LDS = SB 16KB + H 16KB = 32KB ->
// 5 blocks/CU (was 4 at 40KB) -> more co-resident waves to hide each block's
// barrier stalls (the only lever that has moved this kernel: R6 2->4 blocks
// = 161->93us).
//   h1 = relu(concat(nodes[src],eattr,nodes[dst]) @ W0 + b0)  (6 ksteps)
//   h2 = relu(h1 @ W1 + b1)  (2 ksteps);  m = h2 @ W2 + b2  (2 ksteps)
//   LNEPI=0: out[e]=m;  LNEPI=1: out[e]=LN(eattr[e]+m)*g+b
// ---------------------------------------------------------------------------
template<bool LNEPI>
__global__ __launch_bounds__(256, 5)
void fused_mlp3(const unsigned short* __restrict__ nodes,   // [NNODES][128]
                const unsigned short* __restrict__ eattr,   // [E][128]
                const int*            __restrict__ ei,      // [2][E]
                const unsigned short* __restrict__ W0T,     // [128][384]
                const unsigned short* __restrict__ W1T,     // [128][128]
                const unsigned short* __restrict__ W2T,     // [128][128]
                const float* __restrict__ b0, const float* __restrict__ b1,
                const float* __restrict__ b2,
                const float* __restrict__ g,  const float* __restrict__ bb,
                unsigned short* __restrict__ out)           // [E][128]
{
    __shared__ unsigned short SB[128 * 64];    // 16KB W-stage (later LN scratch)
    __shared__ unsigned short H [64 * 128];    // 16KB h1 then h2

    const int tid  = threadIdx.x;
    const int lane = tid & 63;
    const int w    = tid >> 6;
    const int wr   = w >> 1, wc = w & 1;
    const int m0   = blockIdx.x * 64;

    const int lrow = lane >> 3;                   // 0..7 row within an 8-row issue
    const int soff = ((lane & 7) ^ lrow) * 8;     // inverse-swizzled 16B slot (elems)

    char* SBc = (char*)SB;
    char* Hc  = (char*)H;

    // per-lane direct A-row pointers in FRAGMENT layout:
    // frag row = wr*32 + m*16 + (lane&15); elem slot base = (lane>>4)*8
    const int koff = (lane >> 4) * 8;
    const unsigned short *aS[2], *aD[2], *aE[2];
#pragma unroll
    for (int m = 0; m < 2; ++m) {
        int e = m0 + wr * 32 + m * 16 + (lane & 15);
        aS[m] = nodes + (size_t)ei[e]      * 128 + koff;
        aD[m] = nodes + (size_t)ei[E_ + e] * 128 + koff;
        aE[m] = eattr + (size_t)e          * 128 + koff;
    }

    f32x4 acc[2][4];
    auto zacc = [&]() {
#pragma unroll
        for (int m = 0; m < 2; ++m)
#pragma unroll
            for (int n = 0; n < 4; ++n) acc[m][n] = (f32x4){0.f, 0.f, 0.f, 0.f};
    };

    auto stageW = [&](const unsigned short* WT, int Kr, int k0) {
#pragma unroll
        for (int i = 0; i < 4; ++i)
            gl16(WT + (size_t)(w * 32 + i * 8 + lrow) * Kr + k0 + soff,
                 SBc + (w * 32 + i * 8) * 128);
    };

    // MFMA step with A from LDS H (256B rows): used in phases 2/3
    auto mmaH = [&](int kbase) {
#pragma unroll
        for (int ks = 0; ks < 2; ++ks) {
            const int kb = (kbase + ks * 32) * 2 + (lane >> 4) * 16;
            bf16x8 a[2], b[4];
#pragma unroll
            for (int m = 0; m < 2; ++m) {
                int row = wr * 32 + m * 16 + (lane & 15);
                a[m] = *reinterpret_cast<const bf16x8*>(Hc + row * 256 + (kb ^ ((row & 7) << 4)));
            }
            const int kbb = ks * 64 + (lane >> 4) * 16;
#pragma unroll
            for (int n = 0; n < 4; ++n) {
                int row = wc * 64 + n * 16 + (lane & 15);
                b[n] = *reinterpret_cast<const bf16x8*>(SBc + row * 128 + (kbb ^ ((row & 7) << 4)));
            }
#pragma unroll
            for (int m = 0; m < 2; ++m)
#pragma unroll
                for (int n = 0; n < 4; ++n)
                    acc[m][n] = __builtin_amdgcn_mfma_f32_16x16x32_bf16(a[m], b[n], acc[m][n], 0, 0, 0);
        }
    };

    // ---- write activated acc -> H [64][128] bf16, swizzled slots ----
    auto towrite = [&](const float* bias) {
#pragma unroll
        for (int n = 0; n < 4; ++n) {
            int cg = wc * 64 + n * 16 + (lane & 15);
            float bi = bias[cg];
#pragma unroll
            for (int m = 0; m < 2; ++m) {
#pragma unroll
                for (int j = 0; j < 4; ++j) {
                    int rg = wr * 32 + m * 16 + (lane >> 4) * 4 + j;
                    float v = fmaxf(acc[m][n][j] + bi, 0.f);
                    *(unsigned short*)(Hc + rg * 256 + ((2 * cg) ^ ((rg & 7) << 4))) = f2bf(v);
                }
            }
        }
    };

    // ===== phase 1: h1 = relu(X @ W0 + b0), K=384, A direct from global =====
    zacc();
#pragma unroll
    for (int t = 0; t < 6; ++t) {
        stageW(W0T, 384, t * 64);
        bf16x8 areg[2][2];
        const unsigned short* base[2];
#pragma unroll
        for (int m = 0; m < 2; ++m)
            base[m] = (t < 2 ? aS[m] : (t < 4 ? aE[m] : aD[m])) + (t & 1) * 64;
#pragma unroll
        for (int ks = 0; ks < 2; ++ks)
#pragma unroll
            for (int m = 0; m < 2; ++m)
                areg[ks][m] = *reinterpret_cast<const bf16x8*>(base[m] + ks * 32);
        __syncthreads();            // B staged + this wave's a-loads drained
#pragma unroll
        for (int ks = 0; ks < 2; ++ks) {
            const int kbb = ks * 64 + (lane >> 4) * 16;
            bf16x8 b[4];
#pragma unroll
            for (int n = 0; n < 4; ++n) {
                int row = wc * 64 + n * 16 + (lane & 15);
                b[n] = *reinterpret_cast<const bf16x8*>(SBc + row * 128 + (kbb ^ ((row & 7) << 4)));
            }
#pragma unroll
            for (int m = 0; m < 2; ++m)
#pragma unroll
                for (int n = 0; n < 4; ++n)
                    acc[m][n] = __builtin_amdgcn_mfma_f32_16x16x32_bf16(areg[ks][m], b[n], acc[m][n], 0, 0, 0);
        }
        __syncthreads();
    }
    towrite(b0);
    // ===== phase 2: h2 = relu(h1 @ W1 + b1), K=128 =====
    zacc();
#pragma unroll
    for (int k0 = 0; k0 < 128; k0 += 64) {
        stageW(W1T, 128, k0);
        __syncthreads();        // h1 writes + W1 chunk visible
        mmaH(k0);
        __syncthreads();
    }
    towrite(b1);                // h2 over h1: all h1 reads done at loop-final barrier
    // ===== phase 3: m = h2 @ W2 + b2, K=128 =====
    zacc();
#pragma unroll
    for (int k0 = 0; k0 < 128; k0 += 64) {
        stageW(W2T, 128, k0);
        __syncthreads();        // h2 writes + W2 chunk visible
        mmaH(k0);
        __syncthreads();
    }

    // ===== epilogue (R12-proven) =====
    if (!LNEPI) {
#pragma unroll
        for (int n = 0; n < 4; ++n) {
            int cg = wc * 64 + n * 16 + (lane & 15);
            float bi = b2[cg];
#pragma unroll
            for (int m = 0; m < 2; ++m) {
                int rg = m0 + wr * 32 + m * 16 + (lane >> 4) * 4;
                unsigned short* cp = out + (size_t)rg * 128 + cg;
#pragma unroll
                for (int j = 0; j < 4; ++j)
                    cp[(size_t)j * 128] = f2bf(acc[m][n][j] + bi);
            }
        }
    } else {
        // residual + LayerNorm fused. vals = m + b2 + eattr.
#pragma unroll
        for (int n = 0; n < 4; ++n) {
            int cg = wc * 64 + n * 16 + (lane & 15);
            float bi = b2[cg];
#pragma unroll
            for (int m = 0; m < 2; ++m) {
#pragma unroll
                for (int j = 0; j < 4; ++j) {
                    int rg = m0 + wr * 32 + m * 16 + (lane >> 4) * 4 + j;
                    acc[m][n][j] += bi + bf2f(eattr[(size_t)rg * 128 + cg]);
                }
            }
        }
        float* ps = (float*)SBc;          // [2][64] row sums   (SB dead)
        float* pq = ps + 128;             // [2][64] row sumsq
#pragma unroll
        for (int m = 0; m < 2; ++m) {
#pragma unroll
            for (int j = 0; j < 4; ++j) {
                float s = 0.f, q = 0.f;
#pragma unroll
                for (int n = 0; n < 4; ++n) {
                    float v = acc[m][n][j];
                    s += v; q += v * v;
                }
#pragma unroll
                for (int msk = 1; msk < 16; msk <<= 1) {
                    s += __shfl_xor(s, msk);
                    q += __shfl_xor(q, msk);
                }
                if ((lane & 15) == 0) {
                    int rl = wr * 32 + m * 16 + (lane >> 4) * 4 + j;
                    ps[wc * 64 + rl] = s;
                    pq[wc * 64 + rl] = q;
                }
            }
        }
        __syncthreads();
#pragma unroll
        for (int m = 0; m < 2; ++m) {
#pragma unroll
            for (int j = 0; j < 4; ++j) {
                int rl = wr * 32 + m * 16 + (lane >> 4) * 4 + j;
                float S = ps[rl] + ps[64 + rl];
                float Q = pq[rl] + pq[64 + rl];
                float mean = S * (1.f / 128.f);
                float var  = Q * (1.f / 128.f) - mean * mean;
                float rs   = rsqrtf(var + 1e-5f);
                int rg = m0 + rl;
#pragma unroll
                for (int n = 0; n < 4; ++n) {
                    int cg = wc * 64 + n * 16 + (lane & 15);
                    out[(size_t)rg * 128 + cg] =
                        f2bf((acc[m][n][j] - mean) * rs * g[cg] + bb[cg]);
                }
            }
        }
    }
}

// ---------------------------------------------------------------------------
// FF first GEMM: C = relu(A @ W0 + b0), BM=128 tile  [R6 structure]
// ---------------------------------------------------------------------------
template<int BM, int K, int NTOT, bool RELU>
__global__ __launch_bounds__(256)
void mlp_gemm(const unsigned short* __restrict__ Abase,
              const unsigned short* __restrict__ WT,      // [NTOT][K] bf16
              const float*          __restrict__ bias,    // [NTOT] fp32
              unsigned short*       __restrict__ C)       // [M][NTOT] bf16
{
    constexpr int MI = BM / 32;
    __shared__ unsigned short Alds[BM * 64];
    __shared__ unsigned short Blds[128 * 64];

    const int tid  = threadIdx.x;
    const int lane = tid & 63;
    const int w    = tid >> 6;
    const int wr   = w >> 1, wc = w & 1;
    const int m0   = blockIdx.x * BM;
    const int n0   = blockIdx.y * 128;

    const int lrow = lane >> 3;
    const int soff = ((lane & 7) ^ lrow) * 8;

    const unsigned short *pS[MI], *pB[4];
#pragma unroll
    for (int i = 0; i < MI; ++i)
        pS[i] = Abase + (size_t)(m0 + w * (BM / 4) + i * 8 + lrow) * K + soff;
#pragma unroll
    for (int i = 0; i < 4; ++i)
        pB[i] = WT + (size_t)(n0 + w * 32 + i * 8 + lrow) * K + soff;

    f32x4 acc[MI][4];
#pragma unroll
    for (int m = 0; m < MI; ++m)
#pragma unroll
        for (int n = 0; n < 4; ++n) acc[m][n] = (f32x4){0.f, 0.f, 0.f, 0.f};

#pragma unroll
    for (int k0 = 0; k0 < K; k0 += 64) {
#pragma unroll
        for (int i = 0; i < MI; ++i)
            gl16(pS[i] + k0, Alds + (w * (BM / 4) + i * 8) * 64);
#pragma unroll
        for (int i = 0; i < 4; ++i)
            gl16(pB[i] + k0, Blds + (w * 32 + i * 8) * 64);
        __syncthreads();

#pragma unroll
        for (int ks = 0; ks < 2; ++ks) {
            const int kb = ks * 64 + (lane >> 4) * 16;
            bf16x8 a[MI], b[4];
#pragma unroll
            for (int m = 0; m < MI; ++m) {
                int row = wr * (BM / 2) + m * 16 + (lane & 15);
                a[m] = *reinterpret_cast<const bf16x8*>(
                    (const char*)Alds + row * 128 + (kb ^ ((row & 7) << 4)));
            }
#pragma unroll
            for (int n = 0; n < 4; ++n) {
                int row = wc * 64 + n * 16 + (lane & 15);
                b[n] = *reinterpret_cast<const bf16x8*>(
                    (const char*)Blds + row * 128 + (kb ^ ((row & 7) << 4)));
            }
#pragma unroll
            for (int m = 0; m < MI; ++m)
#pragma unroll
                for (int n = 0; n < 4; ++n)
                    acc[m][n] = __builtin_amdgcn_mfma_f32_16x16x32_bf16(a[m], b[n], acc[m][n], 0, 0, 0);
        }
        __syncthreads();
    }

#pragma unroll
    for (int n = 0; n < 4; ++n) {
        int colg = n0 + wc * 64 + n * 16 + (lane & 15);
        float bi = bias[colg];
#pragma unroll
        for (int m = 0; m < MI; ++m) {
            int rowg = m0 + wr * (BM / 2) + m * 16 + (lane >> 4) * 4;
            unsigned short* cp = C + (size_t)rowg * NTOT + colg;
#pragma unroll
            for (int j = 0; j < 4; ++j) {
                float r = acc[m][n][j] + bi;
                if (RELU) r = fmaxf(r, 0.f);
                cp[(size_t)j * NTOT] = f2bf(r);
            }
        }
    }
}

// ---------------------------------------------------------------------------
// FF second GEMM + fused residual + LayerNorm (block owns full rows).
// ---------------------------------------------------------------------------
template<bool F32OUT>
__global__ __launch_bounds__(256)
void ff1_ln(const unsigned short* __restrict__ Abase,   // ffh [M][512]
            const unsigned short* __restrict__ WT,      // [128][512]
            const float* __restrict__ bias,             // [128]
            const unsigned short* __restrict__ resid,   // nodes [M][128]
            const float* __restrict__ g, const float* __restrict__ bb,
            void* __restrict__ outp)
{
    constexpr int K = 512;
    __shared__ unsigned short Alds[64 * 64];    //  8KB
    __shared__ unsigned short Blds[128 * 64];   // 16KB (LN scratch after loop)

    const int tid  = threadIdx.x;
    const int lane = tid & 63;
    const int w    = tid >> 6;
    const int wr   = w >> 1, wc = w & 1;
    const int m0   = blockIdx.x * 64;

    const int lrow = lane >> 3;
    const int soff = ((lane & 7) ^ lrow) * 8;

    const unsigned short *pS[2], *pB[4];
#pragma unroll
    for (int i = 0; i < 2; ++i)
        pS[i] = Abase + (size_t)(m0 + w * 16 + i * 8 + lrow) * K + soff;
#pragma unroll
    for (int i = 0; i < 4; ++i)
        pB[i] = WT + (size_t)(w * 32 + i * 8 + lrow) * K + soff;

    f32x4 acc[2][4];
#pragma unroll
    for (int m = 0; m < 2; ++m)
#pragma unroll
        for (int n = 0; n < 4; ++n) acc[m][n] = (f32x4){0.f, 0.f, 0.f, 0.f};

#pragma unroll
    for (int k0 = 0; k0 < K; k0 += 64) {
#pragma unroll
        for (int i = 0; i < 2; ++i)
            gl16(pS[i] + k0, Alds + (w * 16 + i * 8) * 64);
#pragma unroll
        for (int i = 0; i < 4; ++i)
            gl16(pB[i] + k0, Blds + (w * 32 + i * 8) * 64);
        __syncthreads();

#pragma unroll
        for (int ks = 0; ks < 2; ++ks) {
            const int kb = ks * 64 + (lane >> 4) * 16;
            bf16x8 a[2], b[4];
#pragma unroll
            for (int m = 0; m < 2; ++m) {
                int row = wr * 32 + m * 16 + (lane & 15);
                a[m] = *reinterpret_cast<const bf16x8*>(
                    (const char*)Alds + row * 128 + (kb ^ ((row & 7) << 4)));
            }
#pragma unroll
            for (int n = 0; n < 4; ++n) {
                int row = wc * 64 + n * 16 + (lane & 15);
                b[n] = *reinterpret_cast<const bf16x8*>(
                    (const char*)Blds + row * 128 + (kb ^ ((row & 7) << 4)));
            }
#pragma unroll
            for (int m = 0; m < 2; ++m)
#pragma unroll
                for (int n = 0; n < 4; ++n)
                    acc[m][n] = __builtin_amdgcn_mfma_f32_16x16x32_bf16(a[m], b[n], acc[m][n], 0, 0, 0);
        }
        __syncthreads();
    }

    // ---- residual + bias into acc ----
#pragma unroll
    for (int n = 0; n < 4; ++n) {
        int cg = wc * 64 + n * 16 + (lane & 15);
        float bi = bias[cg];
#pragma unroll
        for (int m = 0; m < 2; ++m) {
#pragma unroll
            for (int j = 0; j < 4; ++j) {
                int rg = m0 + wr * 32 + m * 16 + (lane >> 4) * 4 + j;
                acc[m][n][j] += bi + bf2f(resid[(size_t)rg * 128 + cg]);
            }
        }
    }
    // ---- LN row reduction (Blds scratch) ----
    float* ps = (float*)Blds;         // [2][64] row sums
    float* pq = ps + 128;             // [2][64] row sumsq
#pragma unroll
    for (int m = 0; m < 2; ++m) {
#pragma unroll
        for (int j = 0; j < 4; ++j) {
            float s = 0.f, q = 0.f;
#pragma unroll
            for (int n = 0; n < 4; ++n) {
                float v = acc[m][n][j];
                s += v; q += v * v;
            }
#pragma unroll
            for (int msk = 1; msk < 16; msk <<= 1) {
                s += __shfl_xor(s, msk);
                q += __shfl_xor(q, msk);
            }
            if ((lane & 15) == 0) {
                int rl = wr * 32 + m * 16 + (lane >> 4) * 4 + j;
                ps[wc * 64 + rl] = s;
                pq[wc * 64 + rl] = q;
            }
        }
    }
    __syncthreads();
#pragma unroll
    for (int m = 0; m < 2; ++m) {
#pragma unroll
        for (int j = 0; j < 4; ++j) {
            int rl = wr * 32 + m * 16 + (lane >> 4) * 4 + j;
            float S = ps[rl] + ps[64 + rl];
            float Q = pq[rl] + pq[64 + rl];
            float mean = S * (1.f / 128.f);
            float var  = Q * (1.f / 128.f) - mean * mean;
            float rs   = rsqrtf(var + 1e-5f);
            int rg = m0 + rl;
#pragma unroll
            for (int n = 0; n < 4; ++n) {
                int cg = wc * 64 + n * 16 + (lane & 15);
                float y = (acc[m][n][j] - mean) * rs * g[cg] + bb[cg];
                if (F32OUT) ((float*)outp)[(size_t)rg * 128 + cg] = y;
                else ((unsigned short*)outp)[(size_t)rg * 128 + cg] = f2bf(y);
            }
        }
    }
}

__global__ __launch_bounds__(256)
void k_deg(const int* __restrict__ ei, int* __restrict__ deg)
{
    int e = blockIdx.x * 256 + threadIdx.x;
    atomicAdd(&deg[ei[E_ + e]], 1);
}

// exclusive scan of deg[32768] -> off[32769]
__global__ __launch_bounds__(1024)
void k_scan(const int* __restrict__ deg, int* __restrict__ off)
{
    __shared__ int part[1024];
    const int t = threadIdx.x;
    const int base = t * 32;
    int loc[32];
    int s = 0;
#pragma unroll
    for (int i = 0; i < 32; ++i) { loc[i] = s; s += deg[base + i]; }
    part[t] = s;
    __syncthreads();
    for (int d = 1; d < 1024; d <<= 1) {
        int v = (t >= d) ? part[t - d] : 0;
        __syncthreads();
        part[t] += v;
        __syncthreads();
    }
    const int pre = (t == 0) ? 0 : part[t - 1];
#pragma unroll
    for (int i = 0; i < 32; ++i) off[base + i] = pre + loc[i];
    if (t == 1023) off[NNODES] = pre + s;
}

__global__ __launch_bounds__(256)
void k_bucket(const int* __restrict__ ei, int* __restrict__ cursor, int* __restrict__ elist)
{
    int e = blockIdx.x * 256 + threadIdx.x;
    int d = ei[E_ + e];
    int pos = atomicAdd(&cursor[d], 1);
    elist[pos] = e;
}

// Fused: agg = mean_{e in CSR[v]} m[e];  out = LN(nodes_in[v] + agg).
__global__ __launch_bounds__(256)
void k_aggln(const unsigned short* __restrict__ m,
             const int* __restrict__ off, const int* __restrict__ elist,
             const unsigned short* __restrict__ nodes_in,
             const float* __restrict__ g, const float* __restrict__ bb,
             unsigned short* __restrict__ nodes_out)
{
    const int v    = blockIdx.x * 4 + (threadIdx.x >> 6);
    const int lane = threadIdx.x & 63;
    const int c    = lane * 2;
    const int beg  = off[v], end = off[v + 1];

    float a0 = 0.f, a1 = 0.f;
    for (int i = beg; i < end; ++i) {
        int e = elist[i];
        unsigned int u = *reinterpret_cast<const unsigned int*>(m + (size_t)e * 128 + c);
        a0 += bf2f((unsigned short)(u & 0xffffu));
        a1 += bf2f((unsigned short)(u >> 16));
    }
    const float inv = 1.f / fmaxf((float)(end - beg), 1.f);
    const size_t o = (size_t)v * 128 + c;
    float x0 = bf2f(nodes_in[o])     + a0 * inv;
    float x1 = bf2f(nodes_in[o + 1]) + a1 * inv;

    float s = x0 + x1, sq = x0 * x0 + x1 * x1;
#pragma unroll
    for (int mm = 1; mm < 64; mm <<= 1) { s += __shfl_xor(s, mm); sq += __shfl_xor(sq, mm); }
    float mean = s * (1.f / 128.f);
    float var  = sq * (1.f / 128.f) - mean * mean;
    float rs   = rsqrtf(var + 1e-5f);
    nodes_out[o]     = f2bf((x0 - mean) * rs * g[c]     + bb[c]);
    nodes_out[o + 1] = f2bf((x1 - mean) * rs * g[c + 1] + bb[c + 1]);
}

// ---------------------------------------------------------------------------
extern "C" void kernel_launch(void* const* d_in, const int* in_sizes, int n_in,
                              void* d_out, int out_size, void* d_ws, size_t ws_size,
                              hipStream_t stream)
{
    const float* x      = (const float*)d_in[0];
    const int*   ei     = (const int*)d_in[1];
    const float* eat0   = (const float*)d_in[2];
    const float* msg_W0 = (const float*)d_in[3];
    const float* msg_b0 = (const float*)d_in[4];
    const float* msg_W1 = (const float*)d_in[5];
    const float* msg_b1 = (const float*)d_in[6];
    const float* msg_W2 = (const float*)d_in[7];
    const float* msg_b2 = (const float*)d_in[8];
    const float* n0g    = (const float*)d_in[9];
    const float* n0b    = (const float*)d_in[10];
    const float* ff_W0  = (const float*)d_in[11];
    const float* ff_b0  = (const float*)d_in[12];
    const float* ff_W1  = (const float*)d_in[13];
    const float* ff_b1  = (const float*)d_in[14];
    const float* n1g    = (const float*)d_in[15];
    const float* n1b    = (const float*)d_in[16];
    const float* e_W0   = (const float*)d_in[17];
    const float* e_b0   = (const float*)d_in[18];
    const float* e_W1   = (const float*)d_in[19];
    const float* e_b1   = (const float*)d_in[20];
    const float* e_W2   = (const float*)d_in[21];
    const float* e_b2   = (const float*)d_in[22];
    const float* eng    = (const float*)d_in[23];
    const float* enb    = (const float*)d_in[24];

    char* ws = (char*)d_ws;
    const size_t MB = (size_t)1 << 20;
    unsigned short* nodes = (unsigned short*)(ws);                 // 8 MB bf16
    unsigned short* edgec = (unsigned short*)(ws + 8 * MB);        // 64 MB bf16
    unsigned short* tmpA  = (unsigned short*)(ws + 72 * MB);       // 64 MB (msg out m)
    unsigned short* ffh   = (unsigned short*)(ws + 136 * MB);      // 32 MB (FF hidden)
    unsigned short* wt    = (unsigned short*)(ws + 200 * MB);      // ~1 MB bf16
    int*            deg   = (int*)(ws + 202 * MB);                 // 128 KB
    int*            off   = (int*)(ws + 202 * MB + 256 * 1024);    // 128 KB + 4
    int*            cur   = (int*)(ws + 202 * MB + 512 * 1024);    // 128 KB
    int*            elist = (int*)(ws + 202 * MB + 768 * 1024);    // 1 MB

    // weight transpose targets (bf16 [N][K])
    unsigned short* p = wt;
    unsigned short *wt_m0[L_], *wt_m1[L_], *wt_m2[L_], *wt_f0[L_], *wt_f1[L_];
    for (int l = 0; l < L_; ++l) {
        wt_m0[l] = p; p += 384 * 128;
        wt_m1[l] = p; p += 128 * 128;
        wt_m2[l] = p; p += 128 * 128;
        wt_f0[l] = p; p += 128 * 512;
        wt_f1[l] = p; p += 512 * 128;
    }
    unsigned short* wt_e0 = p; p += 384 * 128;
    unsigned short* wt_e1 = p; p += 128 * 128;
    unsigned short* wt_e2 = p; p += 128 * 128;

    TDA tda; int toff = 0, ti = 0;
    auto addT = [&](const float* s, unsigned short* d, int K, int N) {
        tda.v[ti++] = TD{s, d, toff, K, (N == 512 ? 9 : 7)};
        toff += K * N;
    };
    for (int l = 0; l < L_; ++l) {
        addT(msg_W0 + l * 384 * 128, wt_m0[l], 384, 128);
        addT(msg_W1 + l * 128 * 128, wt_m1[l], 128, 128);
        addT(msg_W2 + l * 128 * 128, wt_m2[l], 128, 128);
        addT(ff_W0  + l * 128 * 512, wt_f0[l], 128, 512);
        addT(ff_W1  + l * 512 * 128, wt_f1[l], 512, 128);
    }
    addT(e_W0, wt_e0, 384, 128);   // layer-0 edge update only (layer-1's is dead code)
    addT(e_W1, wt_e1, 128, 128);
    addT(e_W2, wt_e2, 128, 128);
    tda.total = toff;
    k_transpose_all<<<(toff + 255) / 256, 256, 0, stream>>>(tda);

    const int n4a = NNODES * 128 / 4, n4b = E_ * 128 / 4;
    k_cvt2<<<(n4a + n4b + 255) / 256, 256, 0, stream>>>(x, nodes, n4a, eat0, edgec, n4b);

    // CSR build (once — edge_index constant across layers)
    hipMemsetAsync(deg, 0, NNODES * sizeof(int), stream);
    k_deg<<<E_ / 256, 256, 0, stream>>>(ei, deg);
    k_scan<<<1, 1024, 0, stream>>>(deg, off);
    hipMemcpyAsync(cur, off, NNODES * sizeof(int), hipMemcpyDeviceToDevice, stream);
    k_bucket<<<E_ / 256, 256, 0, stream>>>(ei, cur, elist);

    const dim3 gE(E_ / 64, 1), gN64(NNODES / 64, 1), gF0(NNODES / 128, 4);

    for (int l = 0; l < L_; ++l) {
        // --- fused message MLP (3 GEMMs in one kernel) -> m ---
        fused_mlp3<false><<<gE, 256, 0, stream>>>(nodes, edgec, ei,
            wt_m0[l], wt_m1[l], wt_m2[l],
            msg_b0 + l * 128, msg_b1 + l * 128, msg_b2 + l * 128,
            nullptr, nullptr, tmpA);
        k_aggln<<<NNODES / 4, 256, 0, stream>>>(tmpA, off, elist, nodes,
            n0g + l * 128, n0b + l * 128, nodes);
        // --- feedforward: GEMM1, then GEMM2 fused with residual+LN ---
        mlp_gemm<128, 128, 512, true><<<gF0, 256, 0, stream>>>(nodes, wt_f0[l], ff_b0 + l * 512, ffh);
        if (l == L_ - 1) {
            ff1_ln<true ><<<gN64, 256, 0, stream>>>(ffh, wt_f1[l], ff_b1 + l * 128,
                nodes, n1g + l * 128, n1b + l * 128, d_out);
        } else {
            ff1_ln<false><<<gN64, 256, 0, stream>>>(ffh, wt_f1[l], ff_b1 + l * 128,
                nodes, n1g + l * 128, n1b + l * 128, nodes);
        }
        // --- fused edge update incl. residual+LN (only layer 0; layer-1's is dead) ---
        if (l == 0) {
            fused_mlp3<true><<<gE, 256, 0, stream>>>(nodes, edgec, ei,
                wt_e0, wt_e1, wt_e2, e_b0, e_b1, e_b2, eng, enb, edgec);
        }
    }
}

// Round 15
// 453.292 us; speedup vs baseline: 1.2919x; 1.2919x over previous
//
#include <hip/hip_runtime.h>

#define E_      262144
#define NNODES  32768
#define L_      2

typedef __attribute__((ext_vector_type(8))) short  bf16x8;
typedef __attribute__((ext_vector_type(4))) float  f32x4;

typedef __attribute__((address_space(1))) const unsigned int gu32;
typedef __attribute__((address_space(3))) unsigned int       lu32;

__device__ __forceinline__ void gl16(const void* g, void* l) {
    // async global->LDS, 16B/lane; LDS dest = wave-uniform base + lane*16
    __builtin_amdgcn_global_load_lds((gu32*)g, (lu32*)l, 16, 0, 0);
}

__device__ __forceinline__ float bf2f(unsigned short u) {
    union { unsigned int i; float f; } v; v.i = ((unsigned int)u) << 16; return v.f;
}
__device__ __forceinline__ unsigned short f2bf(float f) {
    union { float f; unsigned int i; } v; v.f = f;
    unsigned int r = v.i + 0x7FFFu + ((v.i >> 16) & 1u);   // round-nearest-even
    return (unsigned short)(r >> 16);
}

// combined fp32->bf16 for nodes + edge_attr
__global__ __launch_bounds__(256)
void k_cvt2(const float* __restrict__ a, unsigned short* __restrict__ oa, int n4a,
            const float* __restrict__ b, unsigned short* __restrict__ ob, int n4b)
{
    int i = blockIdx.x * 256 + threadIdx.x;
    if (i < n4a) {
        float4 v = reinterpret_cast<const float4*>(a)[i];
        ushort4 o; o.x = f2bf(v.x); o.y = f2bf(v.y); o.z = f2bf(v.z); o.w = f2bf(v.w);
        reinterpret_cast<ushort4*>(oa)[i] = o;
    } else if (i < n4a + n4b) {
        int j = i - n4a;
        float4 v = reinterpret_cast<const float4*>(b)[j];
        ushort4 o; o.x = f2bf(v.x); o.y = f2bf(v.y); o.z = f2bf(v.z); o.w = f2bf(v.w);
        reinterpret_cast<ushort4*>(ob)[j] = o;
    }
}

// batched weight transpose: 13 matrices in one dispatch. [K][N] fp32 -> [N][K] bf16
struct TD  { const float* s; unsigned short* d; int off; int K; int nsh; };
struct TDA { TD v[13]; int total; };

__global__ __launch_bounds__(256)
void k_transpose_all(TDA t)
{
    int idx = blockIdx.x * 256 + threadIdx.x;
    if (idx >= t.total) return;
    int j = 0;
#pragma unroll
    for (int m = 1; m < 13; ++m) if (idx >= t.v[m].off) j = m;
    const TD& td = t.v[j];
    int local = idx - td.off;
    int k = local >> td.nsh;
    int n = local & ((1 << td.nsh) - 1);
    td.d[(size_t)n * td.K + k] = f2bf(td.s[local]);
}

// ---------------------------------------------------------------------------
// FUSED 3-stage edge MLP, BM=64 (R6-proven structure: stage->sync->mma->sync,
// K-chunk 64, 40KB LDS -> 4 blocks/CU, launch_bounds(256,4)):
//   h1 = relu(concat(nodes[src],eattr,nodes[dst]) @ W0 + b0)  (6 ksteps)
//   h2 = relu(h1 @ W1 + b1)  (2 ksteps);  m = h2 @ W2 + b2  (2 ksteps)
//   LNEPI=0: out[e]=m;  LNEPI=1: out[e]=LN(eattr[e]+m)*g+b
// This configuration is a verified local optimum: pipelining (R7/R10),
// de-staging (R9/R14), factorization (R8/R11), epilogue relayout (R13) and
// occupancy changes (R14) all regressed in within-session A/B.
// ---------------------------------------------------------------------------
template<bool LNEPI>
__global__ __launch_bounds__(256, 4)
void fused_mlp3(const unsigned short* __restrict__ nodes,   // [NNODES][128]
                const unsigned short* __restrict__ eattr,   // [E][128]
                const int*            __restrict__ ei,      // [2][E]
                const unsigned short* __restrict__ W0T,     // [128][384]
                const unsigned short* __restrict__ W1T,     // [128][128]
                const unsigned short* __restrict__ W2T,     // [128][128]
                const float* __restrict__ b0, const float* __restrict__ b1,
                const float* __restrict__ b2,
                const float* __restrict__ g,  const float* __restrict__ bb,
                unsigned short* __restrict__ out)           // [E][128]
{
    __shared__ unsigned short S0[64 * 64];     //  8KB A-stage
    __shared__ unsigned short SB[128 * 64];    // 16KB W-stage (later LN scratch)
    __shared__ unsigned short H [64 * 128];    // 16KB h1 then h2

    const int tid  = threadIdx.x;
    const int lane = tid & 63;
    const int w    = tid >> 6;
    const int wr   = w >> 1, wc = w & 1;
    const int m0   = blockIdx.x * 64;

    const int lrow = lane >> 3;                   // 0..7 row within an 8-row issue
    const int soff = ((lane & 7) ^ lrow) * 8;     // inverse-swizzled 16B slot (elems)

    char* S0c = (char*)S0;
    char* SBc = (char*)SB;
    char* Hc  = (char*)H;

    // gather pointers: 2 issues of 8 rows per wave => 64 rows
    const unsigned short *pS[2], *pD[2], *pE[2];
#pragma unroll
    for (int i = 0; i < 2; ++i) {
        int r = w * 16 + i * 8 + lrow;
        int e = m0 + r;
        pS[i] = nodes + (size_t)ei[e]      * 128 + soff;
        pD[i] = nodes + (size_t)ei[E_ + e] * 128 + soff;
        pE[i] = eattr + (size_t)e          * 128 + soff;
    }

    f32x4 acc[2][4];
    auto zacc = [&]() {
#pragma unroll
        for (int m = 0; m < 2; ++m)
#pragma unroll
            for (int n = 0; n < 4; ++n) acc[m][n] = (f32x4){0.f, 0.f, 0.f, 0.f};
    };

    // ---- MFMA tile step: A from LDS (row stride abytes), B from SB ----
    auto mma = [&](const char* Ab, int abytes, int kbase) {
#pragma unroll
        for (int ks = 0; ks < 2; ++ks) {
            const int kb = (kbase + ks * 32) * 2 + (lane >> 4) * 16;
            bf16x8 a[2], b[4];
#pragma unroll
            for (int m = 0; m < 2; ++m) {
                int row = wr * 32 + m * 16 + (lane & 15);
                a[m] = *reinterpret_cast<const bf16x8*>(Ab + row * abytes + (kb ^ ((row & 7) << 4)));
            }
            const int kbb = ks * 64 + (lane >> 4) * 16;
#pragma unroll
            for (int n = 0; n < 4; ++n) {
                int row = wc * 64 + n * 16 + (lane & 15);
                b[n] = *reinterpret_cast<const bf16x8*>(SBc + row * 128 + (kbb ^ ((row & 7) << 4)));
            }
#pragma unroll
            for (int m = 0; m < 2; ++m)
#pragma unroll
                for (int n = 0; n < 4; ++n)
                    acc[m][n] = __builtin_amdgcn_mfma_f32_16x16x32_bf16(a[m], b[n], acc[m][n], 0, 0, 0);
        }
    };

    // ---- write activated acc -> H [64][128] bf16, swizzled slots ----
    auto towrite = [&](const float* bias) {
#pragma unroll
        for (int n = 0; n < 4; ++n) {
            int cg = wc * 64 + n * 16 + (lane & 15);
            float bi = bias[cg];
#pragma unroll
            for (int m = 0; m < 2; ++m) {
#pragma unroll
                for (int j = 0; j < 4; ++j) {
                    int rg = wr * 32 + m * 16 + (lane >> 4) * 4 + j;
                    float v = fmaxf(acc[m][n][j] + bi, 0.f);
                    *(unsigned short*)(Hc + rg * 256 + ((2 * cg) ^ ((rg & 7) << 4))) = f2bf(v);
                }
            }
        }
    };

    // ================= phase 1: h1 = relu(X @ W0 + b0), K=384 =================
    zacc();
    for (int k0 = 0; k0 < 384; k0 += 64) {
#pragma unroll
        for (int i = 0; i < 2; ++i) {
            const unsigned short* pa = (k0 < 128 ? pS[i] : (k0 < 256 ? pE[i] : pD[i])) + (k0 & 64);
            gl16(pa, S0c + (w * 16 + i * 8) * 128);
        }
#pragma unroll
        for (int i = 0; i < 4; ++i)
            gl16(W0T + (size_t)(w * 32 + i * 8 + lrow) * 384 + k0 + soff,
                 SBc + (w * 32 + i * 8) * 128);
        __syncthreads();
        mma(S0c, 128, 0);
        __syncthreads();
    }
    towrite(b0);
    // ================= phase 2: h2 = relu(h1 @ W1 + b1), K=128 ================
    zacc();
#pragma unroll
    for (int k0 = 0; k0 < 128; k0 += 64) {
#pragma unroll
        for (int i = 0; i < 4; ++i)
            gl16(W1T + (size_t)(w * 32 + i * 8 + lrow) * 128 + k0 + soff,
                 SBc + (w * 32 + i * 8) * 128);
        __syncthreads();        // h1 writes + W1 chunk visible
        mma(Hc, 256, k0);
        __syncthreads();
    }
    towrite(b1);                // h2 over h1: all h1 reads completed at loop-final barrier
    // ================= phase 3: m = h2 @ W2 + b2, K=128 =======================
    zacc();
#pragma unroll
    for (int k0 = 0; k0 < 128; k0 += 64) {
#pragma unroll
        for (int i = 0; i < 4; ++i)
            gl16(W2T + (size_t)(w * 32 + i * 8 + lrow) * 128 + k0 + soff,
                 SBc + (w * 32 + i * 8) * 128);
        __syncthreads();        // h2 writes + W2 chunk visible
        mma(Hc, 256, k0);
        __syncthreads();
    }

    // ================= epilogue =================
    if (!LNEPI) {
#pragma unroll
        for (int n = 0; n < 4; ++n) {
            int cg = wc * 64 + n * 16 + (lane & 15);
            float bi = b2[cg];
#pragma unroll
            for (int m = 0; m < 2; ++m) {
                int rg = m0 + wr * 32 + m * 16 + (lane >> 4) * 4;
                unsigned short* cp = out + (size_t)rg * 128 + cg;
#pragma unroll
                for (int j = 0; j < 4; ++j)
                    cp[(size_t)j * 128] = f2bf(acc[m][n][j] + bi);
            }
        }
    } else {
        // residual + LayerNorm fused. vals = m + b2 + eattr.
#pragma unroll
        for (int n = 0; n < 4; ++n) {
            int cg = wc * 64 + n * 16 + (lane & 15);
            float bi = b2[cg];
#pragma unroll
            for (int m = 0; m < 2; ++m) {
#pragma unroll
                for (int j = 0; j < 4; ++j) {
                    int rg = m0 + wr * 32 + m * 16 + (lane >> 4) * 4 + j;
                    acc[m][n][j] += bi + bf2f(eattr[(size_t)rg * 128 + cg]);
                }
            }
        }
        float* ps = (float*)SBc;          // [2][64] row sums   (SB dead)
        float* pq = ps + 128;             // [2][64] row sumsq
#pragma unroll
        for (int m = 0; m < 2; ++m) {
#pragma unroll
            for (int j = 0; j < 4; ++j) {
                float s = 0.f, q = 0.f;
#pragma unroll
                for (int n = 0; n < 4; ++n) {
                    float v = acc[m][n][j];
                    s += v; q += v * v;
                }
#pragma unroll
                for (int msk = 1; msk < 16; msk <<= 1) {
                    s += __shfl_xor(s, msk);
                    q += __shfl_xor(q, msk);
                }
                if ((lane & 15) == 0) {
                    int rl = wr * 32 + m * 16 + (lane >> 4) * 4 + j;
                    ps[wc * 64 + rl] = s;
                    pq[wc * 64 + rl] = q;
                }
            }
        }
        __syncthreads();
#pragma unroll
        for (int m = 0; m < 2; ++m) {
#pragma unroll
            for (int j = 0; j < 4; ++j) {
                int rl = wr * 32 + m * 16 + (lane >> 4) * 4 + j;
                float S = ps[rl] + ps[64 + rl];
                float Q = pq[rl] + pq[64 + rl];
                float mean = S * (1.f / 128.f);
                float var  = Q * (1.f / 128.f) - mean * mean;
                float rs   = rsqrtf(var + 1e-5f);
                int rg = m0 + rl;
#pragma unroll
                for (int n = 0; n < 4; ++n) {
                    int cg = wc * 64 + n * 16 + (lane & 15);
                    out[(size_t)rg * 128 + cg] =
                        f2bf((acc[m][n][j] - mean) * rs * g[cg] + bb[cg]);
                }
            }
        }
    }
}

// ---------------------------------------------------------------------------
// FF first GEMM: C = relu(A @ W0 + b0), BM=128 tile  [R6 structure]
// ---------------------------------------------------------------------------
template<int BM, int K, int NTOT, bool RELU>
__global__ __launch_bounds__(256)
void mlp_gemm(const unsigned short* __restrict__ Abase,
              const unsigned short* __restrict__ WT,      // [NTOT][K] bf16
              const float*          __restrict__ bias,    // [NTOT] fp32
              unsigned short*       __restrict__ C)       // [M][NTOT] bf16
{
    constexpr int MI = BM / 32;
    __shared__ unsigned short Alds[BM * 64];
    __shared__ unsigned short Blds[128 * 64];

    const int tid  = threadIdx.x;
    const int lane = tid & 63;
    const int w    = tid >> 6;
    const int wr   = w >> 1, wc = w & 1;
    const int m0   = blockIdx.x * BM;
    const int n0   = blockIdx.y * 128;

    const int lrow = lane >> 3;
    const int soff = ((lane & 7) ^ lrow) * 8;

    const unsigned short *pS[MI], *pB[4];
#pragma unroll
    for (int i = 0; i < MI; ++i)
        pS[i] = Abase + (size_t)(m0 + w * (BM / 4) + i * 8 + lrow) * K + soff;
#pragma unroll
    for (int i = 0; i < 4; ++i)
        pB[i] = WT + (size_t)(n0 + w * 32 + i * 8 + lrow) * K + soff;

    f32x4 acc[MI][4];
#pragma unroll
    for (int m = 0; m < MI; ++m)
#pragma unroll
        for (int n = 0; n < 4; ++n) acc[m][n] = (f32x4){0.f, 0.f, 0.f, 0.f};

#pragma unroll
    for (int k0 = 0; k0 < K; k0 += 64) {
#pragma unroll
        for (int i = 0; i < MI; ++i)
            gl16(pS[i] + k0, Alds + (w * (BM / 4) + i * 8) * 64);
#pragma unroll
        for (int i = 0; i < 4; ++i)
            gl16(pB[i] + k0, Blds + (w * 32 + i * 8) * 64);
        __syncthreads();

#pragma unroll
        for (int ks = 0; ks < 2; ++ks) {
            const int kb = ks * 64 + (lane >> 4) * 16;
            bf16x8 a[MI], b[4];
#pragma unroll
            for (int m = 0; m < MI; ++m) {
                int row = wr * (BM / 2) + m * 16 + (lane & 15);
                a[m] = *reinterpret_cast<const bf16x8*>(
                    (const char*)Alds + row * 128 + (kb ^ ((row & 7) << 4)));
            }
#pragma unroll
            for (int n = 0; n < 4; ++n) {
                int row = wc * 64 + n * 16 + (lane & 15);
                b[n] = *reinterpret_cast<const bf16x8*>(
                    (const char*)Blds + row * 128 + (kb ^ ((row & 7) << 4)));
            }
#pragma unroll
            for (int m = 0; m < MI; ++m)
#pragma unroll
                for (int n = 0; n < 4; ++n)
                    acc[m][n] = __builtin_amdgcn_mfma_f32_16x16x32_bf16(a[m], b[n], acc[m][n], 0, 0, 0);
        }
        __syncthreads();
    }

#pragma unroll
    for (int n = 0; n < 4; ++n) {
        int colg = n0 + wc * 64 + n * 16 + (lane & 15);
        float bi = bias[colg];
#pragma unroll
        for (int m = 0; m < MI; ++m) {
            int rowg = m0 + wr * (BM / 2) + m * 16 + (lane >> 4) * 4;
            unsigned short* cp = C + (size_t)rowg * NTOT + colg;
#pragma unroll
            for (int j = 0; j < 4; ++j) {
                float r = acc[m][n][j] + bi;
                if (RELU) r = fmaxf(r, 0.f);
                cp[(size_t)j * NTOT] = f2bf(r);
            }
        }
    }
}

// ---------------------------------------------------------------------------
// FF second GEMM + fused residual + LayerNorm (block owns full rows).
// ---------------------------------------------------------------------------
template<bool F32OUT>
__global__ __launch_bounds__(256)
void ff1_ln(const unsigned short* __restrict__ Abase,   // ffh [M][512]
            const unsigned short* __restrict__ WT,      // [128][512]
            const float* __restrict__ bias,             // [128]
            const unsigned short* __restrict__ resid,   // nodes [M][128]
            const float* __restrict__ g, const float* __restrict__ bb,
            void* __restrict__ outp)
{
    constexpr int K = 512;
    __shared__ unsigned short Alds[64 * 64];    //  8KB
    __shared__ unsigned short Blds[128 * 64];   // 16KB (LN scratch after loop)

    const int tid  = threadIdx.x;
    const int lane = tid & 63;
    const int w    = tid >> 6;
    const int wr   = w >> 1, wc = w & 1;
    const int m0   = blockIdx.x * 64;

    const int lrow = lane >> 3;
    const int soff = ((lane & 7) ^ lrow) * 8;

    const unsigned short *pS[2], *pB[4];
#pragma unroll
    for (int i = 0; i < 2; ++i)
        pS[i] = Abase + (size_t)(m0 + w * 16 + i * 8 + lrow) * K + soff;
#pragma unroll
    for (int i = 0; i < 4; ++i)
        pB[i] = WT + (size_t)(w * 32 + i * 8 + lrow) * K + soff;

    f32x4 acc[2][4];
#pragma unroll
    for (int m = 0; m < 2; ++m)
#pragma unroll
        for (int n = 0; n < 4; ++n) acc[m][n] = (f32x4){0.f, 0.f, 0.f, 0.f};

#pragma unroll
    for (int k0 = 0; k0 < K; k0 += 64) {
#pragma unroll
        for (int i = 0; i < 2; ++i)
            gl16(pS[i] + k0, Alds + (w * 16 + i * 8) * 64);
#pragma unroll
        for (int i = 0; i < 4; ++i)
            gl16(pB[i] + k0, Blds + (w * 32 + i * 8) * 64);
        __syncthreads();

#pragma unroll
        for (int ks = 0; ks < 2; ++ks) {
            const int kb = ks * 64 + (lane >> 4) * 16;
            bf16x8 a[2], b[4];
#pragma unroll
            for (int m = 0; m < 2; ++m) {
                int row = wr * 32 + m * 16 + (lane & 15);
                a[m] = *reinterpret_cast<const bf16x8*>(
                    (const char*)Alds + row * 128 + (kb ^ ((row & 7) << 4)));
            }
#pragma unroll
            for (int n = 0; n < 4; ++n) {
                int row = wc * 64 + n * 16 + (lane & 15);
                b[n] = *reinterpret_cast<const bf16x8*>(
                    (const char*)Blds + row * 128 + (kb ^ ((row & 7) << 4)));
            }
#pragma unroll
            for (int m = 0; m < 2; ++m)
#pragma unroll
                for (int n = 0; n < 4; ++n)
                    acc[m][n] = __builtin_amdgcn_mfma_f32_16x16x32_bf16(a[m], b[n], acc[m][n], 0, 0, 0);
        }
        __syncthreads();
    }

    // ---- residual + bias into acc ----
#pragma unroll
    for (int n = 0; n < 4; ++n) {
        int cg = wc * 64 + n * 16 + (lane & 15);
        float bi = bias[cg];
#pragma unroll
        for (int m = 0; m < 2; ++m) {
#pragma unroll
            for (int j = 0; j < 4; ++j) {
                int rg = m0 + wr * 32 + m * 16 + (lane >> 4) * 4 + j;
                acc[m][n][j] += bi + bf2f(resid[(size_t)rg * 128 + cg]);
            }
        }
    }
    // ---- LN row reduction (Blds scratch) ----
    float* ps = (float*)Blds;         // [2][64] row sums
    float* pq = ps + 128;             // [2][64] row sumsq
#pragma unroll
    for (int m = 0; m < 2; ++m) {
#pragma unroll
        for (int j = 0; j < 4; ++j) {
            float s = 0.f, q = 0.f;
#pragma unroll
            for (int n = 0; n < 4; ++n) {
                float v = acc[m][n][j];
                s += v; q += v * v;
            }
#pragma unroll
            for (int msk = 1; msk < 16; msk <<= 1) {
                s += __shfl_xor(s, msk);
                q += __shfl_xor(q, msk);
            }
            if ((lane & 15) == 0) {
                int rl = wr * 32 + m * 16 + (lane >> 4) * 4 + j;
                ps[wc * 64 + rl] = s;
                pq[wc * 64 + rl] = q;
            }
        }
    }
    __syncthreads();
#pragma unroll
    for (int m = 0; m < 2; ++m) {
#pragma unroll
        for (int j = 0; j < 4; ++j) {
            int rl = wr * 32 + m * 16 + (lane >> 4) * 4 + j;
            float S = ps[rl] + ps[64 + rl];
            float Q = pq[rl] + pq[64 + rl];
            float mean = S * (1.f / 128.f);
            float var  = Q * (1.f / 128.f) - mean * mean;
            float rs   = rsqrtf(var + 1e-5f);
            int rg = m0 + rl;
#pragma unroll
            for (int n = 0; n < 4; ++n) {
                int cg = wc * 64 + n * 16 + (lane & 15);
                float y = (acc[m][n][j] - mean) * rs * g[cg] + bb[cg];
                if (F32OUT) ((float*)outp)[(size_t)rg * 128 + cg] = y;
                else ((unsigned short*)outp)[(size_t)rg * 128 + cg] = f2bf(y);
            }
        }
    }
}

__global__ __launch_bounds__(256)
void k_deg(const int* __restrict__ ei, int* __restrict__ deg)
{
    int e = blockIdx.x * 256 + threadIdx.x;
    atomicAdd(&deg[ei[E_ + e]], 1);
}

// exclusive scan of deg[32768] -> off[32769]
__global__ __launch_bounds__(1024)
void k_scan(const int* __restrict__ deg, int* __restrict__ off)
{
    __shared__ int part[1024];
    const int t = threadIdx.x;
    const int base = t * 32;
    int loc[32];
    int s = 0;
#pragma unroll
    for (int i = 0; i < 32; ++i) { loc[i] = s; s += deg[base + i]; }
    part[t] = s;
    __syncthreads();
    for (int d = 1; d < 1024; d <<= 1) {
        int v = (t >= d) ? part[t - d] : 0;
        __syncthreads();
        part[t] += v;
        __syncthreads();
    }
    const int pre = (t == 0) ? 0 : part[t - 1];
#pragma unroll
    for (int i = 0; i < 32; ++i) off[base + i] = pre + loc[i];
    if (t == 1023) off[NNODES] = pre + s;
}

__global__ __launch_bounds__(256)
void k_bucket(const int* __restrict__ ei, int* __restrict__ cursor, int* __restrict__ elist)
{
    int e = blockIdx.x * 256 + threadIdx.x;
    int d = ei[E_ + e];
    int pos = atomicAdd(&cursor[d], 1);
    elist[pos] = e;
}

// Fused: agg = mean_{e in CSR[v]} m[e];  out = LN(nodes_in[v] + agg).
__global__ __launch_bounds__(256)
void k_aggln(const unsigned short* __restrict__ m,
             const int* __restrict__ off, const int* __restrict__ elist,
             const unsigned short* __restrict__ nodes_in,
             const float* __restrict__ g, const float* __restrict__ bb,
             unsigned short* __restrict__ nodes_out)
{
    const int v    = blockIdx.x * 4 + (threadIdx.x >> 6);
    const int lane = threadIdx.x & 63;
    const int c    = lane * 2;
    const int beg  = off[v], end = off[v + 1];

    float a0 = 0.f, a1 = 0.f;
    for (int i = beg; i < end; ++i) {
        int e = elist[i];
        unsigned int u = *reinterpret_cast<const unsigned int*>(m + (size_t)e * 128 + c);
        a0 += bf2f((unsigned short)(u & 0xffffu));
        a1 += bf2f((unsigned short)(u >> 16));
    }
    const float inv = 1.f / fmaxf((float)(end - beg), 1.f);
    const size_t o = (size_t)v * 128 + c;
    float x0 = bf2f(nodes_in[o])     + a0 * inv;
    float x1 = bf2f(nodes_in[o + 1]) + a1 * inv;

    float s = x0 + x1, sq = x0 * x0 + x1 * x1;
#pragma unroll
    for (int mm = 1; mm < 64; mm <<= 1) { s += __shfl_xor(s, mm); sq += __shfl_xor(sq, mm); }
    float mean = s * (1.f / 128.f);
    float var  = sq * (1.f / 128.f) - mean * mean;
    float rs   = rsqrtf(var + 1e-5f);
    nodes_out[o]     = f2bf((x0 - mean) * rs * g[c]     + bb[c]);
    nodes_out[o + 1] = f2bf((x1 - mean) * rs * g[c + 1] + bb[c + 1]);
}

// ---------------------------------------------------------------------------
extern "C" void kernel_launch(void* const* d_in, const int* in_sizes, int n_in,
                              void* d_out, int out_size, void* d_ws, size_t ws_size,
                              hipStream_t stream)
{
    const float* x      = (const float*)d_in[0];
    const int*   ei     = (const int*)d_in[1];
    const float* eat0   = (const float*)d_in[2];
    const float* msg_W0 = (const float*)d_in[3];
    const float* msg_b0 = (const float*)d_in[4];
    const float* msg_W1 = (const float*)d_in[5];
    const float* msg_b1 = (const float*)d_in[6];
    const float* msg_W2 = (const float*)d_in[7];
    const float* msg_b2 = (const float*)d_in[8];
    const float* n0g    = (const float*)d_in[9];
    const float* n0b    = (const float*)d_in[10];
    const float* ff_W0  = (const float*)d_in[11];
    const float* ff_b0  = (const float*)d_in[12];
    const float* ff_W1  = (const float*)d_in[13];
    const float* ff_b1  = (const float*)d_in[14];
    const float* n1g    = (const float*)d_in[15];
    const float* n1b    = (const float*)d_in[16];
    const float* e_W0   = (const float*)d_in[17];
    const float* e_b0   = (const float*)d_in[18];
    const float* e_W1   = (const float*)d_in[19];
    const float* e_b1   = (const float*)d_in[20];
    const float* e_W2   = (const float*)d_in[21];
    const float* e_b2   = (const float*)d_in[22];
    const float* eng    = (const float*)d_in[23];
    const float* enb    = (const float*)d_in[24];

    char* ws = (char*)d_ws;
    const size_t MB = (size_t)1 << 20;
    unsigned short* nodes = (unsigned short*)(ws);                 // 8 MB bf16
    unsigned short* edgec = (unsigned short*)(ws + 8 * MB);        // 64 MB bf16
    unsigned short* tmpA  = (unsigned short*)(ws + 72 * MB);       // 64 MB (msg out m)
    unsigned short* ffh   = (unsigned short*)(ws + 136 * MB);      // 32 MB (FF hidden)
    unsigned short* wt    = (unsigned short*)(ws + 200 * MB);      // ~1 MB bf16
    int*            deg   = (int*)(ws + 202 * MB);                 // 128 KB
    int*            off   = (int*)(ws + 202 * MB + 256 * 1024);    // 128 KB + 4
    int*            cur   = (int*)(ws + 202 * MB + 512 * 1024);    // 128 KB
    int*            elist = (int*)(ws + 202 * MB + 768 * 1024);    // 1 MB

    // weight transpose targets (bf16 [N][K])
    unsigned short* p = wt;
    unsigned short *wt_m0[L_], *wt_m1[L_], *wt_m2[L_], *wt_f0[L_], *wt_f1[L_];
    for (int l = 0; l < L_; ++l) {
        wt_m0[l] = p; p += 384 * 128;
        wt_m1[l] = p; p += 128 * 128;
        wt_m2[l] = p; p += 128 * 128;
        wt_f0[l] = p; p += 128 * 512;
        wt_f1[l] = p; p += 512 * 128;
    }
    unsigned short* wt_e0 = p; p += 384 * 128;
    unsigned short* wt_e1 = p; p += 128 * 128;
    unsigned short* wt_e2 = p; p += 128 * 128;

    TDA tda; int toff = 0, ti = 0;
    auto addT = [&](const float* s, unsigned short* d, int K, int N) {
        tda.v[ti++] = TD{s, d, toff, K, (N == 512 ? 9 : 7)};
        toff += K * N;
    };
    for (int l = 0; l < L_; ++l) {
        addT(msg_W0 + l * 384 * 128, wt_m0[l], 384, 128);
        addT(msg_W1 + l * 128 * 128, wt_m1[l], 128, 128);
        addT(msg_W2 + l * 128 * 128, wt_m2[l], 128, 128);
        addT(ff_W0  + l * 128 * 512, wt_f0[l], 128, 512);
        addT(ff_W1  + l * 512 * 128, wt_f1[l], 512, 128);
    }
    addT(e_W0, wt_e0, 384, 128);   // layer-0 edge update only (layer-1's is dead code)
    addT(e_W1, wt_e1, 128, 128);
    addT(e_W2, wt_e2, 128, 128);
    tda.total = toff;
    k_transpose_all<<<(toff + 255) / 256, 256, 0, stream>>>(tda);

    const int n4a = NNODES * 128 / 4, n4b = E_ * 128 / 4;
    k_cvt2<<<(n4a + n4b + 255) / 256, 256, 0, stream>>>(x, nodes, n4a, eat0, edgec, n4b);

    // CSR build (once — edge_index constant across layers)
    hipMemsetAsync(deg, 0, NNODES * sizeof(int), stream);
    k_deg<<<E_ / 256, 256, 0, stream>>>(ei, deg);
    k_scan<<<1, 1024, 0, stream>>>(deg, off);
    hipMemcpyAsync(cur, off, NNODES * sizeof(int), hipMemcpyDeviceToDevice, stream);
    k_bucket<<<E_ / 256, 256, 0, stream>>>(ei, cur, elist);

    const dim3 gE(E_ / 64, 1), gN64(NNODES / 64, 1), gF0(NNODES / 128, 4);

    for (int l = 0; l < L_; ++l) {
        // --- fused message MLP (3 GEMMs in one kernel) -> m ---
        fused_mlp3<false><<<gE, 256, 0, stream>>>(nodes, edgec, ei,
            wt_m0[l], wt_m1[l], wt_m2[l],
            msg_b0 + l * 128, msg_b1 + l * 128, msg_b2 + l * 128,
            nullptr, nullptr, tmpA);
        k_aggln<<<NNODES / 4, 256, 0, stream>>>(tmpA, off, elist, nodes,
            n0g + l * 128, n0b + l * 128, nodes);
        // --- feedforward: GEMM1, then GEMM2 fused with residual+LN ---
        mlp_gemm<128, 128, 512, true><<<gF0, 256, 0, stream>>>(nodes, wt_f0[l], ff_b0 + l * 512, ffh);
        if (l == L_ - 1) {
            ff1_ln<true ><<<gN64, 256, 0, stream>>>(ffh, wt_f1[l], ff_b1 + l * 128,
                nodes, n1g + l * 128, n1b + l * 128, d_out);
        } else {
            ff1_ln<false><<<gN64, 256, 0, stream>>>(ffh, wt_f1[l], ff_b1 + l * 128,
                nodes, n1g + l * 128, n1b + l * 128, nodes);
        }
        // --- fused edge update incl. residual+LN (only layer 0; layer-1's is dead) ---
        if (l == 0) {
            fused_mlp3<true><<<gE, 256, 0, stream>>>(nodes, edgec, ei,
                wt_e0, wt_e1, wt_e2, e_b0, e_b1, e_b2, eng, enb, edgec);
        }
    }
}